// Round 15
// baseline (182.791 us; speedup 1.0000x reference)
//
#include <hip/hip_runtime.h>

// Decorrelation (iterative whitening) normalization.
// Input:  (64, 56, 56, 256) f32, NHWC (C contiguous). N = 200704 positions.
// Groups: 16 groups x 16 channels. Newton-Schulz x5 for Sigma^{-1/2}.
//
// Round-15 (= round-14 with compile fixes: intrinsic spelling; DPP ctrl must
// be a literal, so WPOS unrolls its 4 quad-steps explicitly):
// k_whiten rebuilt with the r12-proven global_load_lds depth-2 pipeline
// (4 KB chunks, LDS double buffer). Counted waits are store-aware: each
// steady iter issues 4 loads + 4 NT stores (in-order retirement), so
// s_waitcnt vmcnt(8) retires exactly the current chunk's loads without
// draining the store queue. k_stats kept at its r12-best config (depth-2,
// 1024 blocks, cpw=49 exact).
//
// ws float layout:
//   [4352, 4608)   : channel means (k_wm)
//   [4608, 8704)   : whitening matrices
//   [8704, A)      : per-block partials, nblk x 4352  (A = 8704+nblk*4352)
//   [A, A+16*4352) : chunk partial sums (k_reduce1 out; k_wm reduces these)

constexpr int CCH = 256;
constexpr float EPSV = 1e-3f;
constexpr int PSTRIDE = 4352;
constexpr int STATBLK = 1024;

typedef float f32x4 __attribute__((ext_vector_type(4)));
typedef unsigned int u32;

__device__ __forceinline__ void gload16(const float* g, float* l) {
    __builtin_amdgcn_global_load_lds(
        (const __attribute__((address_space(1))) u32*)g,
        (__attribute__((address_space(3))) u32*)l, 16, 0, 0);
}

#define WAIT8 asm volatile("s_waitcnt vmcnt(8)" ::: "memory")
#define WAIT4 asm volatile("s_waitcnt vmcnt(4)" ::: "memory")
#define WAIT0 asm volatile("s_waitcnt vmcnt(0)" ::: "memory")

// DPP quad_perm broadcast of lane (quad_base + S) within each 4-lane quad.
#define QB(S, comp) __int_as_float(__builtin_amdgcn_update_dpp( \
    0, __float_as_int(comp), (S) * 0x55, 0xF, 0xF, 1))
// DPP quad rotate: lane r reads lane (r+1)&3 / (r+2)&3 of its quad.
#define ROT1(comp) __int_as_float(__builtin_amdgcn_update_dpp( \
    0, __float_as_int(comp), 0x39, 0xF, 0xF, 1))
#define ROT2(comp) __int_as_float(__builtin_amdgcn_update_dpp( \
    0, __float_as_int(comp), 0x4E, 0xF, 0xF, 1))

#define FMA4(C, V, U) \
    { C.x += (V).x * (U); C.y += (V).y * (U); C.z += (V).z * (U); C.w += (V).w * (U); }

// Per-position accumulate: sums, diag upper-tri, rot1 block, rot2 block. (46 accums)
#define ACCPOS(V)                                                         \
    {                                                                     \
        ss.x += (V).x; ss.y += (V).y; ss.z += (V).z; ss.w += (V).w;       \
        d0 += (V).x * (V).x; d1 += (V).x * (V).y;                         \
        d2 += (V).x * (V).z; d3 += (V).x * (V).w;                         \
        d4 += (V).y * (V).y; d5 += (V).y * (V).z;                         \
        d6 += (V).y * (V).w; d7 += (V).z * (V).z;                         \
        d8 += (V).z * (V).w; d9 += (V).w * (V).w;                         \
        {                                                                 \
            float4 u;                                                     \
            u.x = ROT1((V).x); u.y = ROT1((V).y);                         \
            u.z = ROT1((V).z); u.w = ROT1((V).w);                         \
            FMA4(mA, u, (V).x) FMA4(mB, u, (V).y)                         \
            FMA4(mC, u, (V).z) FMA4(mD, u, (V).w)                         \
        }                                                                 \
        {                                                                 \
            float4 u;                                                     \
            u.x = ROT2((V).x); u.y = ROT2((V).y);                         \
            u.z = ROT2((V).z); u.w = ROT2((V).w);                         \
            FMA4(nA, u, (V).x) FMA4(nB, u, (V).y)                         \
            FMA4(nC, u, (V).z) FMA4(nD, u, (V).w)                         \
        }                                                                 \
    }

// Merge slot layout: cov[g][i][j] at g*260 + i*16 + j; sums at 4160+channel.
#define SW(RI, CJ, VAL)  sl[gbase + (RI) * 16 + (CJ)] = (VAL);
#define SWM(RI, CJ, VAL) { sl[gbase + (RI) * 16 + (CJ)] = (VAL); \
                           sl[gbase + (CJ) * 16 + (RI)] = (VAL); }
#define SR(RI, CJ, VAR)  VAR += sl[gbase + (RI) * 16 + (CJ)];

#define SLOT_WRITE()                                                        \
    {                                                                       \
        const int R = 4 * rr, A = 4 * c1, B = 4 * c2;                       \
        SW(R+0, R+0, d0) SWM(R+0, R+1, d1) SWM(R+0, R+2, d2)                \
        SWM(R+0, R+3, d3) SW(R+1, R+1, d4) SWM(R+1, R+2, d5)                \
        SWM(R+1, R+3, d6) SW(R+2, R+2, d7) SWM(R+2, R+3, d8)                \
        SW(R+3, R+3, d9)                                                    \
        SWM(R+0, A+0, mA.x) SWM(R+0, A+1, mA.y) SWM(R+0, A+2, mA.z)         \
        SWM(R+0, A+3, mA.w) SWM(R+1, A+0, mB.x) SWM(R+1, A+1, mB.y)         \
        SWM(R+1, A+2, mB.z) SWM(R+1, A+3, mB.w) SWM(R+2, A+0, mC.x)         \
        SWM(R+2, A+1, mC.y) SWM(R+2, A+2, mC.z) SWM(R+2, A+3, mC.w)         \
        SWM(R+3, A+0, mD.x) SWM(R+3, A+1, mD.y) SWM(R+3, A+2, mD.z)         \
        SWM(R+3, A+3, mD.w)                                                 \
        SW(R+0, B+0, nA.x) SW(R+0, B+1, nA.y) SW(R+0, B+2, nA.z)            \
        SW(R+0, B+3, nA.w) SW(R+1, B+0, nB.x) SW(R+1, B+1, nB.y)            \
        SW(R+1, B+2, nB.z) SW(R+1, B+3, nB.w) SW(R+2, B+0, nC.x)            \
        SW(R+2, B+1, nC.y) SW(R+2, B+2, nC.z) SW(R+2, B+3, nC.w)            \
        SW(R+3, B+0, nD.x) SW(R+3, B+1, nD.y) SW(R+3, B+2, nD.z)            \
        SW(R+3, B+3, nD.w)                                                  \
        sl[4160 + lane * 4 + 0] = ss.x; sl[4160 + lane * 4 + 1] = ss.y;     \
        sl[4160 + lane * 4 + 2] = ss.z; sl[4160 + lane * 4 + 3] = ss.w;     \
    }

#define SLOT_ADD()                                                          \
    {                                                                       \
        const int R = 4 * rr, A = 4 * c1, B = 4 * c2;                       \
        SR(R+0, R+0, d0) SR(R+0, R+1, d1) SR(R+0, R+2, d2)                  \
        SR(R+0, R+3, d3) SR(R+1, R+1, d4) SR(R+1, R+2, d5)                  \
        SR(R+1, R+3, d6) SR(R+2, R+2, d7) SR(R+2, R+3, d8)                  \
        SR(R+3, R+3, d9)                                                    \
        SR(R+0, A+0, mA.x) SR(R+0, A+1, mA.y) SR(R+0, A+2, mA.z)            \
        SR(R+0, A+3, mA.w) SR(R+1, A+0, mB.x) SR(R+1, A+1, mB.y)            \
        SR(R+1, A+2, mB.z) SR(R+1, A+3, mB.w) SR(R+2, A+0, mC.x)            \
        SR(R+2, A+1, mC.y) SR(R+2, A+2, mC.z) SR(R+2, A+3, mC.w)            \
        SR(R+3, A+0, mD.x) SR(R+3, A+1, mD.y) SR(R+3, A+2, mD.z)            \
        SR(R+3, A+3, mD.w)                                                  \
        SR(R+0, B+0, nA.x) SR(R+0, B+1, nA.y) SR(R+0, B+2, nA.z)            \
        SR(R+0, B+3, nA.w) SR(R+1, B+0, nB.x) SR(R+1, B+1, nB.y)            \
        SR(R+1, B+2, nB.z) SR(R+1, B+3, nB.w) SR(R+2, B+0, nC.x)            \
        SR(R+2, B+1, nC.y) SR(R+2, B+2, nC.z) SR(R+2, B+3, nC.w)            \
        SR(R+3, B+0, nD.x) SR(R+3, B+1, nD.y) SR(R+3, B+2, nD.z)            \
        SR(R+3, B+3, nD.w)                                                  \
        ss.x += sl[4160 + lane * 4 + 0]; ss.y += sl[4160 + lane * 4 + 1];   \
        ss.z += sl[4160 + lane * 4 + 2]; ss.w += sl[4160 + lane * 4 + 3];   \
    }

// Issue one 4-position chunk (4 KB) into BUF via global_load_lds (4 ops).
#define ISSUE(BUF, C)                                                       \
    {                                                                       \
        const float* gp = x + (size_t)(start + 4 * (C)) * CCH + lane * 4;   \
        gload16(gp,           (BUF));                                       \
        gload16(gp + CCH,     (BUF) + 256);                                 \
        gload16(gp + 2 * CCH, (BUF) + 512);                                 \
        gload16(gp + 3 * CCH, (BUF) + 768);                                 \
    }

#define PROC(BUF)                                                           \
    {                                                                       \
        const float4 v0 = *reinterpret_cast<const float4*>((BUF) + lane * 4);        \
        const float4 v1 = *reinterpret_cast<const float4*>((BUF) + 256 + lane * 4);  \
        const float4 v2 = *reinterpret_cast<const float4*>((BUF) + 512 + lane * 4);  \
        const float4 v3 = *reinterpret_cast<const float4*>((BUF) + 768 + lane * 4);  \
        ACCPOS(v0); ACCPOS(v1); ACCPOS(v2); ACCPOS(v3);                     \
    }

__global__ __launch_bounds__(256, 4) void k_stats(const float* __restrict__ x,
                                                  float* __restrict__ partial,
                                                  int npos) {
    const int tid = threadIdx.x;
    const int lane = tid & 63;
    const int w = tid >> 6;
    const int wid = blockIdx.x * 4 + w;
    const int nwaves = gridDim.x * 4;
    const int g = lane >> 2;
    const int rr = lane & 3;
    const int c1 = (rr + 1) & 3;
    const int c2 = (rr + 2) & 3;
    const int gbase = g * 260;

    float4 ss = {0.f, 0.f, 0.f, 0.f};
    float d0 = 0.f, d1 = 0.f, d2 = 0.f, d3 = 0.f, d4 = 0.f, d5 = 0.f,
          d6 = 0.f, d7 = 0.f, d8 = 0.f, d9 = 0.f;
    float4 mA = ss, mB = ss, mC = ss, mD = ss;
    float4 nA = ss, nB = ss, nC = ss, nD = ss;

    // Per-wave LDS double buffer (2 x 4 KB); merge slot aliases lds[0..4416).
    __shared__ float lds[8192];
    float* b0 = &lds[w * 2048];
    float* b1 = b0 + 1024;

    // Contiguous per-wave range. npos=200704, nwaves=4096 -> cpw=49 exact.
    const int cpw = (npos + nwaves - 1) / nwaves;
    const int start = wid * cpw;
    const int end = (start + cpw < npos) ? start + cpw : npos;
    const int n = (end > start) ? end - start : 0;
    const int nf4 = n >> 2;

    if (nf4 >= 2) {
        ISSUE(b0, 0);
        ISSUE(b1, 1);
        int i = 0;
        for (; i + 2 < nf4; ++i) {          // steady state: 8 loads in flight
            WAIT4;
            float* bb = (i & 1) ? b1 : b0;
            PROC(bb);
            ISSUE(bb, i + 2);
        }
        WAIT4;
        PROC(((i & 1) ? b1 : b0));
        ++i;
        WAIT0;
        PROC(((i & 1) ? b1 : b0));
    } else if (nf4 == 1) {
        ISSUE(b0, 0);
        WAIT0;
        PROC(b0);
    }
    // Tail positions (n % 4): plain loads.
    for (int q = start + 4 * nf4; q < end; ++q) {
        const float4 v = *reinterpret_cast<const float4*>(x + (size_t)q * CCH + lane * 4);
        ACCPOS(v);
    }

    // Block merge: atomic-free tree through the (now free) LDS slot.
    float* sl = lds;
    __syncthreads();

    if (w == 1) SLOT_WRITE();
    __syncthreads();
    if (w == 0) SLOT_ADD();
    __syncthreads();
    if (w == 3) SLOT_WRITE();
    __syncthreads();
    if (w == 2) SLOT_ADD();
    __syncthreads();
    if (w == 2) SLOT_WRITE();
    __syncthreads();
    if (w == 0) { SLOT_ADD(); SLOT_WRITE(); }
    __syncthreads();

    // Cooperative coalesced copy: LDS slot -> global partial record.
    float* rec = partial + (size_t)blockIdx.x * PSTRIDE;
    for (int c = tid; c < 256; c += blockDim.x)
        rec[c] = sl[4160 + c];
    for (int e = tid; e < 4096; e += blockDim.x) {
        const int gg = e >> 8, row = (e >> 4) & 15, col = e & 15;
        rec[256 + e] = sl[gg * 260 + row * 16 + col];
    }
}

// Level 1: sum 64-record chunks -> p2[chunk][e]. No atomics.
__global__ __launch_bounds__(256) void k_reduce1(const float* __restrict__ partial,
                                                 float* __restrict__ p2,
                                                 int nblk, int nchunks) {
    const int t = blockIdx.x * blockDim.x + threadIdx.x;
    const int total = nchunks * PSTRIDE;
    if (t >= total) return;
    const int chunk = t / PSTRIDE;
    const int e = t - chunk * PSTRIDE;
    const int r0 = chunk * 64;
    const int rend = (r0 + 64 < nblk) ? r0 + 64 : nblk;
    const float* src = partial + (size_t)r0 * PSTRIDE + e;
    float acc = 0.f;
    for (int r = r0; r < rend; ++r, src += PSTRIDE) acc += *src;
    p2[(size_t)chunk * PSTRIDE + e] = acc;
}

// One block per group; fuses the final chunk reduction (over p2) with the
// Newton-Schulz iteration. Thread (i,j) owns element (i,j).
__global__ __launch_bounds__(256) void k_wm(const float* __restrict__ p2,
                                            int nchunks,
                                            float* __restrict__ mean,
                                            float* __restrict__ wm,
                                            float inv_n) {
    const int g = blockIdx.x;
    const int tid = threadIdx.x;
    const int i = tid >> 4;
    const int j = tid & 15;

    __shared__ float mu[16];
    __shared__ float sig[16][17];
    __shared__ float P[16][17];
    __shared__ float T[16][17];
    __shared__ float U[16][17];

    // Reduce this group's cov element across chunk sums.
    float cs = 0.f;
    {
        const float* s = p2 + 256 + g * 256 + i * 16 + j;
        for (int c = 0; c < nchunks; ++c, s += PSTRIDE) cs += *s;
    }
    if (tid < 16) {
        float ms = 0.f;
        const float* s = p2 + g * 16 + tid;
        for (int c = 0; c < nchunks; ++c, s += PSTRIDE) ms += *s;
        const float m = ms * inv_n;
        mu[tid] = m;
        mean[g * 16 + tid] = m;
    }
    __syncthreads();

    const float cov = cs * inv_n - mu[i] * mu[j];
    const float s = (1.0f - EPSV) * cov + ((i == j) ? EPSV : 0.0f);
    sig[i][j] = s;
    __syncthreads();

    float tr = 0.f;
#pragma unroll
    for (int k = 0; k < 16; ++k) tr += sig[k][k];
    __syncthreads();

    sig[i][j] = s / tr;               // sigma_n
    P[i][j] = (i == j) ? 1.0f : 0.0f;
    __syncthreads();

    for (int it = 0; it < 5; ++it) {
        float a = 0.f;
#pragma unroll
        for (int k = 0; k < 16; ++k) a += P[i][k] * P[k][j];
        T[i][j] = a;
        __syncthreads();

        float b = 0.f;
#pragma unroll
        for (int k = 0; k < 16; ++k) b += T[i][k] * P[k][j];
        U[i][j] = b;
        __syncthreads();

        float c = 0.f;
#pragma unroll
        for (int k = 0; k < 16; ++k) c += U[i][k] * sig[k][j];
        const float pn = 1.5f * P[i][j] - 0.5f * c;
        __syncthreads();
        P[i][j] = pn;
        __syncthreads();
    }

    wm[(g * 16 + i) * 16 + j] = P[i][j] * rsqrtf(tr);
}

// One quad-step of the whitening dot product (literal S only -- DPP ctrl
// must be a compile-time constant).
#define WQ(S)                                                               \
    {                                                                       \
        const float u0 = QB(S, vv.x), u1 = QB(S, vv.y),                     \
                    u2 = QB(S, vv.z), u3 = QB(S, vv.w);                     \
        a0 += wr[0][(S) * 4 + 0] * u0 + wr[0][(S) * 4 + 1] * u1             \
            + wr[0][(S) * 4 + 2] * u2 + wr[0][(S) * 4 + 3] * u3;            \
        a1 += wr[1][(S) * 4 + 0] * u0 + wr[1][(S) * 4 + 1] * u1             \
            + wr[1][(S) * 4 + 2] * u2 + wr[1][(S) * 4 + 3] * u3;            \
        a2 += wr[2][(S) * 4 + 0] * u0 + wr[2][(S) * 4 + 1] * u1             \
            + wr[2][(S) * 4 + 2] * u2 + wr[2][(S) * 4 + 3] * u3;            \
        a3 += wr[3][(S) * 4 + 0] * u0 + wr[3][(S) * 4 + 1] * u1             \
            + wr[3][(S) * 4 + 2] * u2 + wr[3][(S) * 4 + 3] * u3;            \
    }

// Whiten one position's float4 and NT-store it.
#define WPOS(V, POSIDX)                                                     \
    {                                                                       \
        float4 vv = (V);                                                    \
        vv.x -= mu4.x; vv.y -= mu4.y; vv.z -= mu4.z; vv.w -= mu4.w;         \
        float a0 = 0.f, a1 = 0.f, a2 = 0.f, a3 = 0.f;                       \
        WQ(0) WQ(1) WQ(2) WQ(3)                                             \
        f32x4 o;                                                            \
        o.x = a0; o.y = a1; o.z = a2; o.w = a3;                             \
        __builtin_nontemporal_store(o,                                      \
            reinterpret_cast<f32x4*>(out + (size_t)(POSIDX) * CCH + lane * 4)); \
    }

// Process a 4-position chunk from LDS buffer and NT-store results.
#define WPROC(BUF, C)                                                       \
    {                                                                       \
        const int pbase = start + 4 * (C);                                  \
        const float4 v0 = *reinterpret_cast<const float4*>((BUF) + lane * 4);        \
        const float4 v1 = *reinterpret_cast<const float4*>((BUF) + 256 + lane * 4);  \
        const float4 v2 = *reinterpret_cast<const float4*>((BUF) + 512 + lane * 4);  \
        const float4 v3 = *reinterpret_cast<const float4*>((BUF) + 768 + lane * 4);  \
        WPOS(v0, pbase) WPOS(v1, pbase + 1)                                 \
        WPOS(v2, pbase + 2) WPOS(v3, pbase + 3)                             \
    }

__global__ __launch_bounds__(256, 4) void k_whiten(const float* __restrict__ x,
                                                   const float* __restrict__ mean,
                                                   const float* __restrict__ wm,
                                                   float* __restrict__ out,
                                                   int npos) {
    const int tid = threadIdx.x;
    const int lane = tid & 63;
    const int w = tid >> 6;
    const int wid = blockIdx.x * 4 + w;
    const int nwaves = gridDim.x * 4;
    const int g = lane >> 2;
    const int i0 = (lane & 3) * 4;

    // Per-lane whitening rows: 4 output channels x 16 input channels.
    float wr[4][16];
    const float* wg = wm + g * 256;
#pragma unroll
    for (int a = 0; a < 4; ++a)
#pragma unroll
        for (int j = 0; j < 16; ++j) wr[a][j] = wg[(i0 + a) * 16 + j];

    const float4 mu4 = *reinterpret_cast<const float4*>(mean + lane * 4);

    // Per-wave LDS double buffer (2 x 4 KB).
    __shared__ float lds[8192];
    float* b0 = &lds[w * 2048];
    float* b1 = b0 + 1024;

    // Contiguous per-wave range. npos=200704, nwaves=4096 -> cpw=49 exact.
    const int cpw = (npos + nwaves - 1) / nwaves;
    const int start = wid * cpw;
    const int end = (start + cpw < npos) ? start + cpw : npos;
    const int n = (end > start) ? end - start : 0;
    const int nf4 = n >> 2;

    if (nf4 >= 2) {
        ISSUE(b0, 0);
        ISSUE(b1, 1);
        int i = 0;
        if (i + 2 < nf4) {
            // First iteration: no stores outstanding yet.
            WAIT4;
            WPROC(b0, 0);
            ISSUE(b0, 2);
            ++i;
            // Steady state: outstanding = S(i-2),L(i),S(i-1),L(i+1) <= 16;
            // WAIT8 retires the oldest 8, guaranteeing chunk i's loads.
            for (; i + 2 < nf4; ++i) {
                WAIT8;
                float* bb = (i & 1) ? b1 : b0;
                WPROC(bb, i);
                ISSUE(bb, i + 2);
            }
            WAIT8;
            WPROC(((i & 1) ? b1 : b0), i);
            ++i;
            WAIT4;
            WPROC(((i & 1) ? b1 : b0), i);
        } else {
            WAIT4;
            WPROC(b0, 0);
            WAIT4;          // retires L1 (stores issued after it don't block)
            WPROC(b1, 1);
        }
    } else if (nf4 == 1) {
        ISSUE(b0, 0);
        WAIT0;
        WPROC(b0, 0);
    }
    // Tail positions (n % 4): plain loads.
    for (int q = start + 4 * nf4; q < end; ++q) {
        const float4 v = *reinterpret_cast<const float4*>(x + (size_t)q * CCH + lane * 4);
        WPOS(v, q);
    }
}

extern "C" void kernel_launch(void* const* d_in, const int* in_sizes, int n_in,
                              void* d_out, int out_size, void* d_ws, size_t ws_size,
                              hipStream_t stream) {
    const float* x = (const float*)d_in[0];
    float* out = (float*)d_out;
    float* ws = (float*)d_ws;

    const int total = in_sizes[0];
    const int npos = total / CCH;   // 200704
    const float inv_n = 1.0f / (float)npos;

    float* mean = ws + 4352;
    float* wm = ws + 4608;
    float* partial = ws + 8704;    // nblk * PSTRIDE floats

    long avail = (long)(ws_size / 4) - 8704 - 16 * PSTRIDE;
    int nblk = (int)(avail / PSTRIDE);
    if (nblk > STATBLK) nblk = STATBLK;
    if (nblk < 64) nblk = 64;

    float* p2 = partial + (size_t)nblk * PSTRIDE;   // 16 * PSTRIDE floats

    k_stats<<<nblk, 256, 0, stream>>>(x, partial, npos);
    const int nchunks = (nblk + 63) / 64;           // <= 16
    const int r1threads = nchunks * PSTRIDE;
    k_reduce1<<<(r1threads + 255) / 256, 256, 0, stream>>>(partial, p2, nblk, nchunks);
    k_wm<<<16, 256, 0, stream>>>(p2, nchunks, mean, wm, inv_n);
    k_whiten<<<1024, 256, 0, stream>>>(x, mean, wm, out, npos);
}

// Round 16
// 137.036 us; speedup vs baseline: 1.3339x; 1.3339x over previous
//
#include <hip/hip_runtime.h>

// Decorrelation (iterative whitening) normalization.
// Input:  (64, 56, 56, 256) f32, NHWC (C contiguous). N = 200704 positions.
// Groups: 16 groups x 16 channels. Newton-Schulz x5 for Sigma^{-1/2}.
//
// Round-16: REVERT to the round-12 best (139.6 us). Round-15's k_whiten
// counted-vmcnt pipeline regressed 31%: vmcnt counts STORES too, and with
// nontemporal stores (bypass L2, retire at HBM write-ack) WAIT8's oldest-8
// window [S(i-2)x4, L(i)x4] serialized every iteration on store completion.
// Rule: never place stores inside a counted-vmcnt load window.
//
// r12 structure: k_stats = global_load_lds depth-2 pipeline (4 KB chunks,
// per-wave LDS double buffer, counted vmcnt(4) loads-only window);
// k_whiten = VGPR depth-1 prefetch + NT stores (compiler waitcnt tracks
// loads only; NT stores drain fire-and-forget).
//
// ws float layout:
//   [4352, 4608)   : channel means (k_wm)
//   [4608, 8704)   : whitening matrices
//   [8704, A)      : per-block partials, nblk x 4352  (A = 8704+nblk*4352)
//   [A, A+16*4352) : chunk partial sums (k_reduce1 out; k_wm reduces these)

constexpr int CCH = 256;
constexpr float EPSV = 1e-3f;
constexpr int PSTRIDE = 4352;
constexpr int STATBLK = 1024;

typedef float f32x4 __attribute__((ext_vector_type(4)));
typedef unsigned int u32;

__device__ __forceinline__ void gload16(const float* g, float* l) {
    __builtin_amdgcn_global_load_lds(
        (const __attribute__((address_space(1))) u32*)g,
        (__attribute__((address_space(3))) u32*)l, 16, 0, 0);
}

#define WAIT4 asm volatile("s_waitcnt vmcnt(4)" ::: "memory")
#define WAIT0 asm volatile("s_waitcnt vmcnt(0)" ::: "memory")

// DPP quad_perm broadcast of lane (quad_base + S) within each 4-lane quad.
#define QB(S, comp) __int_as_float(__builtin_amdgcn_update_dpp( \
    0, __float_as_int(comp), (S) * 0x55, 0xF, 0xF, 1))
// DPP quad rotate: lane r reads lane (r+1)&3 / (r+2)&3 of its quad.
#define ROT1(comp) __int_as_float(__builtin_amdgcn_update_dpp( \
    0, __float_as_int(comp), 0x39, 0xF, 0xF, 1))
#define ROT2(comp) __int_as_float(__builtin_amdgcn_update_dpp( \
    0, __float_as_int(comp), 0x4E, 0xF, 0xF, 1))

#define FMA4(C, V, U) \
    { C.x += (V).x * (U); C.y += (V).y * (U); C.z += (V).z * (U); C.w += (V).w * (U); }

// Per-position accumulate: sums, diag upper-tri, rot1 block, rot2 block. (46 accums)
#define ACCPOS(V)                                                         \
    {                                                                     \
        ss.x += (V).x; ss.y += (V).y; ss.z += (V).z; ss.w += (V).w;       \
        d0 += (V).x * (V).x; d1 += (V).x * (V).y;                         \
        d2 += (V).x * (V).z; d3 += (V).x * (V).w;                         \
        d4 += (V).y * (V).y; d5 += (V).y * (V).z;                         \
        d6 += (V).y * (V).w; d7 += (V).z * (V).z;                         \
        d8 += (V).z * (V).w; d9 += (V).w * (V).w;                         \
        {                                                                 \
            float4 u;                                                     \
            u.x = ROT1((V).x); u.y = ROT1((V).y);                         \
            u.z = ROT1((V).z); u.w = ROT1((V).w);                         \
            FMA4(mA, u, (V).x) FMA4(mB, u, (V).y)                         \
            FMA4(mC, u, (V).z) FMA4(mD, u, (V).w)                         \
        }                                                                 \
        {                                                                 \
            float4 u;                                                     \
            u.x = ROT2((V).x); u.y = ROT2((V).y);                         \
            u.z = ROT2((V).z); u.w = ROT2((V).w);                         \
            FMA4(nA, u, (V).x) FMA4(nB, u, (V).y)                         \
            FMA4(nC, u, (V).z) FMA4(nD, u, (V).w)                         \
        }                                                                 \
    }

// Merge slot layout: cov[g][i][j] at g*260 + i*16 + j; sums at 4160+channel.
#define SW(RI, CJ, VAL)  sl[gbase + (RI) * 16 + (CJ)] = (VAL);
#define SWM(RI, CJ, VAL) { sl[gbase + (RI) * 16 + (CJ)] = (VAL); \
                           sl[gbase + (CJ) * 16 + (RI)] = (VAL); }
#define SR(RI, CJ, VAR)  VAR += sl[gbase + (RI) * 16 + (CJ)];

#define SLOT_WRITE()                                                        \
    {                                                                       \
        const int R = 4 * rr, A = 4 * c1, B = 4 * c2;                       \
        SW(R+0, R+0, d0) SWM(R+0, R+1, d1) SWM(R+0, R+2, d2)                \
        SWM(R+0, R+3, d3) SW(R+1, R+1, d4) SWM(R+1, R+2, d5)                \
        SWM(R+1, R+3, d6) SW(R+2, R+2, d7) SWM(R+2, R+3, d8)                \
        SW(R+3, R+3, d9)                                                    \
        SWM(R+0, A+0, mA.x) SWM(R+0, A+1, mA.y) SWM(R+0, A+2, mA.z)         \
        SWM(R+0, A+3, mA.w) SWM(R+1, A+0, mB.x) SWM(R+1, A+1, mB.y)         \
        SWM(R+1, A+2, mB.z) SWM(R+1, A+3, mB.w) SWM(R+2, A+0, mC.x)         \
        SWM(R+2, A+1, mC.y) SWM(R+2, A+2, mC.z) SWM(R+2, A+3, mC.w)         \
        SWM(R+3, A+0, mD.x) SWM(R+3, A+1, mD.y) SWM(R+3, A+2, mD.z)         \
        SWM(R+3, A+3, mD.w)                                                 \
        SW(R+0, B+0, nA.x) SW(R+0, B+1, nA.y) SW(R+0, B+2, nA.z)            \
        SW(R+0, B+3, nA.w) SW(R+1, B+0, nB.x) SW(R+1, B+1, nB.y)            \
        SW(R+1, B+2, nB.z) SW(R+1, B+3, nB.w) SW(R+2, B+0, nC.x)            \
        SW(R+2, B+1, nC.y) SW(R+2, B+2, nC.z) SW(R+2, B+3, nC.w)            \
        SW(R+3, B+0, nD.x) SW(R+3, B+1, nD.y) SW(R+3, B+2, nD.z)            \
        SW(R+3, B+3, nD.w)                                                  \
        sl[4160 + lane * 4 + 0] = ss.x; sl[4160 + lane * 4 + 1] = ss.y;     \
        sl[4160 + lane * 4 + 2] = ss.z; sl[4160 + lane * 4 + 3] = ss.w;     \
    }

#define SLOT_ADD()                                                          \
    {                                                                       \
        const int R = 4 * rr, A = 4 * c1, B = 4 * c2;                       \
        SR(R+0, R+0, d0) SR(R+0, R+1, d1) SR(R+0, R+2, d2)                  \
        SR(R+0, R+3, d3) SR(R+1, R+1, d4) SR(R+1, R+2, d5)                  \
        SR(R+1, R+3, d6) SR(R+2, R+2, d7) SR(R+2, R+3, d8)                  \
        SR(R+3, R+3, d9)                                                    \
        SR(R+0, A+0, mA.x) SR(R+0, A+1, mA.y) SR(R+0, A+2, mA.z)            \
        SR(R+0, A+3, mA.w) SR(R+1, A+0, mB.x) SR(R+1, A+1, mB.y)            \
        SR(R+1, A+2, mB.z) SR(R+1, A+3, mB.w) SR(R+2, A+0, mC.x)            \
        SR(R+2, A+1, mC.y) SR(R+2, A+2, mC.z) SR(R+2, A+3, mC.w)            \
        SR(R+3, A+0, mD.x) SR(R+3, A+1, mD.y) SR(R+3, A+2, mD.z)            \
        SR(R+3, A+3, mD.w)                                                  \
        SR(R+0, B+0, nA.x) SR(R+0, B+1, nA.y) SR(R+0, B+2, nA.z)            \
        SR(R+0, B+3, nA.w) SR(R+1, B+0, nB.x) SR(R+1, B+1, nB.y)            \
        SR(R+1, B+2, nB.z) SR(R+1, B+3, nB.w) SR(R+2, B+0, nC.x)            \
        SR(R+2, B+1, nC.y) SR(R+2, B+2, nC.z) SR(R+2, B+3, nC.w)            \
        SR(R+3, B+0, nD.x) SR(R+3, B+1, nD.y) SR(R+3, B+2, nD.z)            \
        SR(R+3, B+3, nD.w)                                                  \
        ss.x += sl[4160 + lane * 4 + 0]; ss.y += sl[4160 + lane * 4 + 1];   \
        ss.z += sl[4160 + lane * 4 + 2]; ss.w += sl[4160 + lane * 4 + 3];   \
    }

// Issue one 4-position chunk (4 KB) into BUF via global_load_lds (4 ops).
#define ISSUE(BUF, C)                                                       \
    {                                                                       \
        const float* gp = x + (size_t)(start + 4 * (C)) * CCH + lane * 4;   \
        gload16(gp,           (BUF));                                       \
        gload16(gp + CCH,     (BUF) + 256);                                 \
        gload16(gp + 2 * CCH, (BUF) + 512);                                 \
        gload16(gp + 3 * CCH, (BUF) + 768);                                 \
    }

#define PROC(BUF)                                                           \
    {                                                                       \
        const float4 v0 = *reinterpret_cast<const float4*>((BUF) + lane * 4);        \
        const float4 v1 = *reinterpret_cast<const float4*>((BUF) + 256 + lane * 4);  \
        const float4 v2 = *reinterpret_cast<const float4*>((BUF) + 512 + lane * 4);  \
        const float4 v3 = *reinterpret_cast<const float4*>((BUF) + 768 + lane * 4);  \
        ACCPOS(v0); ACCPOS(v1); ACCPOS(v2); ACCPOS(v3);                     \
    }

__global__ __launch_bounds__(256, 4) void k_stats(const float* __restrict__ x,
                                                  float* __restrict__ partial,
                                                  int npos) {
    const int tid = threadIdx.x;
    const int lane = tid & 63;
    const int w = tid >> 6;
    const int wid = blockIdx.x * 4 + w;
    const int nwaves = gridDim.x * 4;
    const int g = lane >> 2;
    const int rr = lane & 3;
    const int c1 = (rr + 1) & 3;
    const int c2 = (rr + 2) & 3;
    const int gbase = g * 260;

    float4 ss = {0.f, 0.f, 0.f, 0.f};
    float d0 = 0.f, d1 = 0.f, d2 = 0.f, d3 = 0.f, d4 = 0.f, d5 = 0.f,
          d6 = 0.f, d7 = 0.f, d8 = 0.f, d9 = 0.f;
    float4 mA = ss, mB = ss, mC = ss, mD = ss;
    float4 nA = ss, nB = ss, nC = ss, nD = ss;

    // Per-wave LDS double buffer (2 x 4 KB); merge slot aliases lds[0..4416).
    __shared__ float lds[8192];
    float* b0 = &lds[w * 2048];
    float* b1 = b0 + 1024;

    // Contiguous per-wave range. npos=200704, nwaves=4096 -> cpw=49 exact.
    const int cpw = (npos + nwaves - 1) / nwaves;
    const int start = wid * cpw;
    const int end = (start + cpw < npos) ? start + cpw : npos;
    const int n = (end > start) ? end - start : 0;
    const int nf4 = n >> 2;

    if (nf4 >= 2) {
        ISSUE(b0, 0);
        ISSUE(b1, 1);
        int i = 0;
        for (; i + 2 < nf4; ++i) {          // steady state: 8 loads in flight
            WAIT4;
            float* bb = (i & 1) ? b1 : b0;
            PROC(bb);
            ISSUE(bb, i + 2);
        }
        WAIT4;
        PROC(((i & 1) ? b1 : b0));
        ++i;
        WAIT0;
        PROC(((i & 1) ? b1 : b0));
    } else if (nf4 == 1) {
        ISSUE(b0, 0);
        WAIT0;
        PROC(b0);
    }
    // Tail positions (n % 4): plain loads.
    for (int q = start + 4 * nf4; q < end; ++q) {
        const float4 v = *reinterpret_cast<const float4*>(x + (size_t)q * CCH + lane * 4);
        ACCPOS(v);
    }

    // Block merge: atomic-free tree through the (now free) LDS slot.
    float* sl = lds;
    __syncthreads();

    if (w == 1) SLOT_WRITE();
    __syncthreads();
    if (w == 0) SLOT_ADD();
    __syncthreads();
    if (w == 3) SLOT_WRITE();
    __syncthreads();
    if (w == 2) SLOT_ADD();
    __syncthreads();
    if (w == 2) SLOT_WRITE();
    __syncthreads();
    if (w == 0) { SLOT_ADD(); SLOT_WRITE(); }
    __syncthreads();

    // Cooperative coalesced copy: LDS slot -> global partial record.
    float* rec = partial + (size_t)blockIdx.x * PSTRIDE;
    for (int c = tid; c < 256; c += blockDim.x)
        rec[c] = sl[4160 + c];
    for (int e = tid; e < 4096; e += blockDim.x) {
        const int gg = e >> 8, row = (e >> 4) & 15, col = e & 15;
        rec[256 + e] = sl[gg * 260 + row * 16 + col];
    }
}

// Level 1: sum 64-record chunks -> p2[chunk][e]. No atomics.
__global__ __launch_bounds__(256) void k_reduce1(const float* __restrict__ partial,
                                                 float* __restrict__ p2,
                                                 int nblk, int nchunks) {
    const int t = blockIdx.x * blockDim.x + threadIdx.x;
    const int total = nchunks * PSTRIDE;
    if (t >= total) return;
    const int chunk = t / PSTRIDE;
    const int e = t - chunk * PSTRIDE;
    const int r0 = chunk * 64;
    const int rend = (r0 + 64 < nblk) ? r0 + 64 : nblk;
    const float* src = partial + (size_t)r0 * PSTRIDE + e;
    float acc = 0.f;
    for (int r = r0; r < rend; ++r, src += PSTRIDE) acc += *src;
    p2[(size_t)chunk * PSTRIDE + e] = acc;
}

// One block per group; fuses the final chunk reduction (over p2) with the
// Newton-Schulz iteration. Thread (i,j) owns element (i,j).
__global__ __launch_bounds__(256) void k_wm(const float* __restrict__ p2,
                                            int nchunks,
                                            float* __restrict__ mean,
                                            float* __restrict__ wm,
                                            float inv_n) {
    const int g = blockIdx.x;
    const int tid = threadIdx.x;
    const int i = tid >> 4;
    const int j = tid & 15;

    __shared__ float mu[16];
    __shared__ float sig[16][17];
    __shared__ float P[16][17];
    __shared__ float T[16][17];
    __shared__ float U[16][17];

    // Reduce this group's cov element across chunk sums.
    float cs = 0.f;
    {
        const float* s = p2 + 256 + g * 256 + i * 16 + j;
        for (int c = 0; c < nchunks; ++c, s += PSTRIDE) cs += *s;
    }
    if (tid < 16) {
        float ms = 0.f;
        const float* s = p2 + g * 16 + tid;
        for (int c = 0; c < nchunks; ++c, s += PSTRIDE) ms += *s;
        const float m = ms * inv_n;
        mu[tid] = m;
        mean[g * 16 + tid] = m;
    }
    __syncthreads();

    const float cov = cs * inv_n - mu[i] * mu[j];
    const float s = (1.0f - EPSV) * cov + ((i == j) ? EPSV : 0.0f);
    sig[i][j] = s;
    __syncthreads();

    float tr = 0.f;
#pragma unroll
    for (int k = 0; k < 16; ++k) tr += sig[k][k];
    __syncthreads();

    sig[i][j] = s / tr;               // sigma_n
    P[i][j] = (i == j) ? 1.0f : 0.0f;
    __syncthreads();

    for (int it = 0; it < 5; ++it) {
        float a = 0.f;
#pragma unroll
        for (int k = 0; k < 16; ++k) a += P[i][k] * P[k][j];
        T[i][j] = a;
        __syncthreads();

        float b = 0.f;
#pragma unroll
        for (int k = 0; k < 16; ++k) b += T[i][k] * P[k][j];
        U[i][j] = b;
        __syncthreads();

        float c = 0.f;
#pragma unroll
        for (int k = 0; k < 16; ++k) c += U[i][k] * sig[k][j];
        const float pn = 1.5f * P[i][j] - 0.5f * c;
        __syncthreads();
        P[i][j] = pn;
        __syncthreads();
    }

    wm[(g * 16 + i) * 16 + j] = P[i][j] * rsqrtf(tr);
}

__global__ __launch_bounds__(256) void k_whiten(const float* __restrict__ x,
                                                const float* __restrict__ mean,
                                                const float* __restrict__ wm,
                                                float* __restrict__ out,
                                                int npos) {
    const int tid = threadIdx.x;
    const int lane = tid & 63;
    const int wave = blockIdx.x * (blockDim.x >> 6) + (tid >> 6);
    const int nwaves = gridDim.x * (blockDim.x >> 6);
    const int g = lane >> 2;
    const int i0 = (lane & 3) * 4;

    // Per-lane whitening rows: 4 output channels x 16 input channels.
    float w[4][16];
    const float* wg = wm + g * 256;
#pragma unroll
    for (int a = 0; a < 4; ++a)
#pragma unroll
        for (int j = 0; j < 16; ++j) w[a][j] = wg[(i0 + a) * 16 + j];

    const float4 mu4 = *reinterpret_cast<const float4*>(mean + lane * 4);
    const float* bx = x + lane * 4;
    float* bo = out + lane * 4;

    int p = wave;
    if (p >= npos) return;
    float4 v = *reinterpret_cast<const float4*>(bx + (size_t)p * CCH);
    while (true) {
        const int pn = p + nwaves;
        const bool more = pn < npos;
        float4 vn = v;
        if (more) vn = *reinterpret_cast<const float4*>(bx + (size_t)pn * CCH);

        v.x -= mu4.x; v.y -= mu4.y; v.z -= mu4.z; v.w -= mu4.w;
        float acc[4] = {0.f, 0.f, 0.f, 0.f};
#define WSTEP(S)                                                         \
        {                                                                \
            const float u0 = QB(S, v.x), u1 = QB(S, v.y),                \
                        u2 = QB(S, v.z), u3 = QB(S, v.w);                \
            _Pragma("unroll")                                            \
            for (int a = 0; a < 4; ++a) {                                \
                acc[a] += w[a][(S) * 4 + 0] * u0 + w[a][(S) * 4 + 1] * u1 \
                        + w[a][(S) * 4 + 2] * u2 + w[a][(S) * 4 + 3] * u3; \
            }                                                            \
        }
        WSTEP(0) WSTEP(1) WSTEP(2) WSTEP(3)
#undef WSTEP
        // Nontemporal store: out is write-once -- keep it out of L2/L3 so
        // the input stays cache-resident for the next k_stats.
        f32x4 o;
        o.x = acc[0]; o.y = acc[1]; o.z = acc[2]; o.w = acc[3];
        __builtin_nontemporal_store(o, reinterpret_cast<f32x4*>(bo + (size_t)p * CCH));

        if (!more) break;
        p = pn;
        v = vn;
    }
}

extern "C" void kernel_launch(void* const* d_in, const int* in_sizes, int n_in,
                              void* d_out, int out_size, void* d_ws, size_t ws_size,
                              hipStream_t stream) {
    const float* x = (const float*)d_in[0];
    float* out = (float*)d_out;
    float* ws = (float*)d_ws;

    const int total = in_sizes[0];
    const int npos = total / CCH;   // 200704
    const float inv_n = 1.0f / (float)npos;

    float* mean = ws + 4352;
    float* wm = ws + 4608;
    float* partial = ws + 8704;    // nblk * PSTRIDE floats

    long avail = (long)(ws_size / 4) - 8704 - 16 * PSTRIDE;
    int nblk = (int)(avail / PSTRIDE);
    if (nblk > STATBLK) nblk = STATBLK;
    if (nblk < 64) nblk = 64;

    float* p2 = partial + (size_t)nblk * PSTRIDE;   // 16 * PSTRIDE floats

    k_stats<<<nblk, 256, 0, stream>>>(x, partial, npos);
    const int nchunks = (nblk + 63) / 64;           // <= 16
    const int r1threads = nchunks * PSTRIDE;
    k_reduce1<<<(r1threads + 255) / 256, 256, 0, stream>>>(partial, p2, nblk, nchunks);
    k_wm<<<16, 256, 0, stream>>>(p2, nchunks, mean, wm, inv_n);
    k_whiten<<<2048, 256, 0, stream>>>(x, mean, wm, out, npos);
}